// Round 2
// baseline (361.406 us; speedup 1.0000x reference)
//
#include <hip/hip_runtime.h>

typedef __attribute__((ext_vector_type(8))) short bf16x8;
typedef __attribute__((ext_vector_type(4))) float f32x4;
typedef __attribute__((ext_vector_type(4))) unsigned int u32x4;
typedef __attribute__((ext_vector_type(2))) unsigned int u32x2;

#define NTOK 4096
#define CHD 256
// (1/sqrt(256)) * log2(e) folded into wq/bq so softmax uses exp2 directly
#define QSCALE 0.09016844005556022f
#define KB 32
#define NIT 32            // iterations per key-stream (1024 keys / KB)

typedef unsigned int __attribute__((address_space(1))) gu32;
typedef unsigned int __attribute__((address_space(3))) lu32;
#define GLOAD(g, s) __builtin_amdgcn_global_load_lds((const gu32*)(const void*)(g), (lu32*)(void*)(s), 16, 0, 0)

__device__ __forceinline__ unsigned short f2bf(float x) {
    unsigned int u = __builtin_bit_cast(unsigned int, x);
    return (unsigned short)((u + 0x7FFFu + ((u >> 16) & 1u)) >> 16);
}
__device__ __forceinline__ float bf2f(unsigned short u) {
    return __builtin_bit_cast(float, (unsigned int)u << 16);
}
__device__ __forceinline__ f32x4 mfma16(bf16x8 a, bf16x8 b, f32x4 c) {
    return __builtin_amdgcn_mfma_f32_16x16x32_bf16(a, b, c, 0, 0, 0);
}
template <int CTRL>
__device__ __forceinline__ float dppmv(float x) {
    return __builtin_bit_cast(float,
        __builtin_amdgcn_update_dpp(0, __builtin_bit_cast(int, x), CTRL, 0xF, 0xF, true));
}
// all-reduce over the 16-lane row (keys dimension) via DPP row rotations (VALU-only)
__device__ __forceinline__ float rowmax16(float x) {
    x = fmaxf(x, dppmv<0x128>(x));   // row_ror:8
    x = fmaxf(x, dppmv<0x124>(x));   // row_ror:4
    x = fmaxf(x, dppmv<0x122>(x));   // row_ror:2
    x = fmaxf(x, dppmv<0x121>(x));   // row_ror:1
    return x;
}
__device__ __forceinline__ float rowsum16(float x) {
    x += dppmv<0x128>(x);
    x += dppmv<0x124>(x);
    x += dppmv<0x122>(x);
    x += dppmv<0x121>(x);
    return x;
}

// ---------------- kernel 1: weights fp32 -> bf16 (wq scaled) ----------------
__global__ __launch_bounds__(256) void wconv_kernel(
    const float* __restrict__ wq, const float* __restrict__ wk,
    const float* __restrict__ wv, unsigned short* __restrict__ wbf)
{
    int idx = blockIdx.x * 256 + threadIdx.x;     // 3*65536 total
    int z = idx >> 16;
    const float* src = (z == 0) ? wq : (z == 1) ? wk : wv;
    float s = (z == 0) ? QSCALE : 1.0f;
    wbf[idx] = f2bf(src[idx & 65535] * s);
}

// ---------------- kernel 2: fused 1x1-conv projection -----------------------
__global__ __launch_bounds__(256) void proj_kernel(
    const float* __restrict__ xq, const float* __restrict__ xk, const float* __restrict__ xv,
    const float* __restrict__ bq, const float* __restrict__ bk, const float* __restrict__ bv,
    const unsigned short* __restrict__ wbf,
    unsigned short* __restrict__ Qo, unsigned short* __restrict__ Ko,
    unsigned short* __restrict__ VTo)
{
    __shared__ __align__(16) unsigned short alds[64 * 264];
    __shared__ __align__(16) unsigned char wlds[16384];
    const int z = blockIdx.y;
    const int b = blockIdx.x >> 6;
    const int n0 = (blockIdx.x & 63) << 6;
    const float* x    = (z == 0) ? xq : (z == 1) ? xk : xv;
    const float* bias = (z == 0) ? bq : (z == 1) ? bk : bv;
    const unsigned short* w = wbf + z * 65536;
    const int t = threadIdx.x;
    const int wv_ = t >> 6, l = t & 63, lr = l & 15, lg = l >> 4;

    #pragma unroll
    for (int it = 0; it < 16; ++it) {
        int idx = it * 256 + t;
        int c = idx >> 4, j4 = idx & 15;
        f32x4 v = *(const f32x4*)(x + (size_t)(b * CHD + c) * NTOK + n0 + j4 * 4);
        #pragma unroll
        for (int i = 0; i < 4; ++i)
            alds[(j4 * 4 + i) * 264 + c] = f2bf(v[i]);
    }
    __syncthreads();

    bf16x8 af[8];
    #pragma unroll
    for (int kk = 0; kk < 8; ++kk)
        af[kk] = *(const bf16x8*)&alds[(wv_ * 16 + lr) * 264 + kk * 32 + lg * 8];

    const float bsc = (z == 0) ? QSCALE : 1.0f;

    for (int dg = 0; dg < 8; ++dg) {
        __syncthreads();
        #pragma unroll
        for (int it = 0; it < 4; ++it) {
            int idx = it * 256 + t;
            int dr = idx >> 5, c16 = idx & 31;
            u32x4 vv = *(const u32x4*)(w + (size_t)(dg * 32 + dr) * CHD + c16 * 8);
            *(u32x4*)(wlds + ((dr * 512 + c16 * 16) ^ ((dr & 7) << 4))) = vv;
        }
        __syncthreads();
        #pragma unroll
        for (int dbi = 0; dbi < 2; ++dbi) {
            int dr = dbi * 16 + lr;
            int d = dg * 32 + dr;
            float bias_v = bias[d] * bsc;
            f32x4 acc = {bias_v, bias_v, bias_v, bias_v};
            #pragma unroll
            for (int kk = 0; kk < 8; ++kk) {
                bf16x8 bf = *(const bf16x8*)(wlds + ((dr * 512 + kk * 64 + lg * 16) ^ ((dr & 7) << 4)));
                acc = mfma16(af[kk], bf, acc);
            }
            if (z < 2) {
                unsigned short* o = (z == 0) ? Qo : Ko;
                #pragma unroll
                for (int r = 0; r < 4; ++r) {
                    int n = n0 + wv_ * 16 + lg * 4 + r;
                    o[(size_t)(b * NTOK + n) * CHD + d] = f2bf(acc[r]);
                }
            } else {
                int n = n0 + wv_ * 16 + lg * 4;
                u32x2 pk;
                pk[0] = (unsigned)f2bf(acc[0]) | ((unsigned)f2bf(acc[1]) << 16);
                pk[1] = (unsigned)f2bf(acc[2]) | ((unsigned)f2bf(acc[3]) << 16);
                *(u32x2*)(VTo + (size_t)(b * CHD + d) * NTOK + n) = pk;
            }
        }
    }
}

// ---------------- kernel 3: flash attention -------------------------------
// grid 256, block 512 (8 waves). g=bid&7 -> (b,hf); qtile = bid>>3 (128 rows).
// waves 0-3: keys [kvbase, +1024); waves 4-7: keys [kvbase+1024, +1024).
// Double-buffered K/V staged via global_load_lds; intra-block LSE merge.
//
// LDS map (163840 B): stream s at s*73728:
//   K dbuf: +bsel*16384 (32 rows x 512B, swz ^((row&7)<<4))
//   V dbuf: +32768+bsel*20480 (256 rows x 80B pitch, 64B data)
// P scratch: 147456 + w*2048 (32 rows x 64B, swz ^(((off>>8)&3)<<4))
__global__ __launch_bounds__(512, 2) void attn_kernel(
    const unsigned short* __restrict__ Qp,
    const unsigned short* __restrict__ Kp,
    const unsigned short* __restrict__ VTp,
    unsigned short* __restrict__ Opart,
    float* __restrict__ Mpart, float* __restrict__ Lpart)
{
    __shared__ __align__(16) char smem[163840];
    const int bid = blockIdx.x;
    const int g = bid & 7, b = g >> 1, hf = g & 1;
    const int n0 = (bid >> 3) * 128;
    const int t = threadIdx.x;
    const int w = t >> 6, l = t & 63, lr = l & 15, lg = l >> 4;
    const int sidx = w >> 2, qw = w & 3;
    const int kvw = hf * 2048 + sidx * 1024;

    const char* Kby = (const char*)(Kp + (size_t)b * NTOK * CHD);
    const char* Vby = (const char*)(VTp + (size_t)b * CHD * NTOK);
    const unsigned short* Qb = Qp + (size_t)b * NTOK * CHD;

    char* sb = smem + sidx * 73728;
    char* pbase = smem + 147456 + w * 2048;

    // per-lane staging offsets (within-tile, swizzle baked in)
    int offsK[4], offsV[5];
    #pragma unroll
    for (int j = 0; j < 4; ++j) {
        int o = (j * 4 + qw) * 1024 + l * 16;
        int row = o >> 9;
        offsK[j] = o ^ ((row & 7) << 4);
    }
    #pragma unroll
    for (int j = 0; j < 5; ++j) {
        int o = (j * 4 + qw) * 1024 + l * 16;
        int d = o / 80;
        int m = o - d * 80;
        offsV[j] = d * 8192 + (m < 64 ? m : 0);
    }

    // Q fragments FIRST (so their vmcnt waits don't drain the stage queue)
    bf16x8 qf[2][8];
    #pragma unroll
    for (int nb = 0; nb < 2; ++nb)
        #pragma unroll
        for (int kk = 0; kk < 8; ++kk)
            qf[nb][kk] = *(const bf16x8*)(Qb + (size_t)(n0 + qw * 32 + nb * 16 + lr) * CHD + kk * 32 + lg * 8);

    auto stage = [&](int bsel, int kt2) {
        const char* ks = Kby + (size_t)(kvw + kt2 * KB) * 512;
        const char* vs = Vby + (size_t)kvw * 2 + kt2 * (KB * 2);
        char* kd = sb + bsel * 16384 + qw * 1024;
        char* vd = sb + 32768 + bsel * 20480 + qw * 1024;
        #pragma unroll
        for (int j = 0; j < 4; ++j) GLOAD(ks + offsK[j], kd + j * 4096);
        #pragma unroll
        for (int j = 0; j < 5; ++j) GLOAD(vs + offsV[j], vd + j * 4096);
    };

    stage(0, 0);
    stage(1, 1);

    f32x4 o[2][16];
    #pragma unroll
    for (int nb = 0; nb < 2; ++nb)
        #pragma unroll
        for (int db = 0; db < 16; ++db)
            o[nb][db] = (f32x4){0.f, 0.f, 0.f, 0.f};
    f32x4 mrow[2], lrow[2];
    #pragma unroll
    for (int nb = 0; nb < 2; ++nb) {
        mrow[nb] = (f32x4){-1e30f, -1e30f, -1e30f, -1e30f};
        lrow[nb] = (f32x4){0.f, 0.f, 0.f, 0.f};
    }

    #pragma unroll 1
    for (int kt = 0; kt < NIT; ++kt) {
        const int cur = kt & 1;
        if (kt < NIT - 1) asm volatile("s_waitcnt vmcnt(9)" ::: "memory");
        else              asm volatile("s_waitcnt vmcnt(0)" ::: "memory");
        __builtin_amdgcn_s_barrier();                 // tile kt resident for all waves

        const char* kB = sb + cur * 16384;
        const char* vB = sb + 32768 + cur * 20480;

        // ---- S = Q K^T ----
        f32x4 s[2][2];
        #pragma unroll
        for (int nb = 0; nb < 2; ++nb)
            #pragma unroll
            for (int cb = 0; cb < 2; ++cb)
                s[nb][cb] = (f32x4){0.f, 0.f, 0.f, 0.f};
        __builtin_amdgcn_s_setprio(1);
        #pragma unroll
        for (int kk = 0; kk < 8; ++kk) {
            bf16x8 kf0 = *(const bf16x8*)(kB + ((lr * 512 + kk * 64 + lg * 16) ^ ((lr & 7) << 4)));
            bf16x8 kf1 = *(const bf16x8*)(kB + (((16 + lr) * 512 + kk * 64 + lg * 16) ^ ((lr & 7) << 4)));
            s[0][0] = mfma16(qf[0][kk], kf0, s[0][0]);
            s[1][0] = mfma16(qf[1][kk], kf0, s[1][0]);
            s[0][1] = mfma16(qf[0][kk], kf1, s[0][1]);
            s[1][1] = mfma16(qf[1][kk], kf1, s[1][1]);
        }
        __builtin_amdgcn_s_setprio(0);

        // ---- online softmax (keys live along the 16-lane row) ----
        f32x4 resc[2], psum[2];
        bool grow = false;
        #pragma unroll
        for (int nb = 0; nb < 2; ++nb) {
            #pragma unroll
            for (int r = 0; r < 4; ++r) {
                float mx = rowmax16(fmaxf(s[nb][0][r], s[nb][1][r]));
                float mo = mrow[nb][r];
                float mn = fmaxf(mo, mx);
                mrow[nb][r] = mn;
                resc[nb][r] = __builtin_amdgcn_exp2f(mo - mn);
                grow = grow || (mn > mo);
            }
        }
        if (__any((int)grow)) {
            #pragma unroll
            for (int nb = 0; nb < 2; ++nb) {
                #pragma unroll
                for (int db = 0; db < 16; ++db)
                    o[nb][db] *= resc[nb];
                lrow[nb] *= resc[nb];
            }
        }
        #pragma unroll
        for (int nb = 0; nb < 2; ++nb) {
            #pragma unroll
            for (int r = 0; r < 4; ++r) {
                float a0 = __builtin_amdgcn_exp2f(s[nb][0][r] - mrow[nb][r]);
                float a1 = __builtin_amdgcn_exp2f(s[nb][1][r] - mrow[nb][r]);
                s[nb][0][r] = a0; s[nb][1][r] = a1;
                psum[nb][r] = rowsum16(a0 + a1);
            }
            lrow[nb] += psum[nb];
        }

        // ---- P -> bf16 through per-wave LDS scratch (transpose to A-frag) ----
        #pragma unroll
        for (int nb = 0; nb < 2; ++nb)
            #pragma unroll
            for (int cb = 0; cb < 2; ++cb)
                #pragma unroll
                for (int r = 0; r < 4; ++r) {
                    int off = (nb * 16 + lg * 4 + r) * 64 + (cb * 16 + lr) * 2;
                    *(unsigned short*)(pbase + (off ^ (((off >> 8) & 3) << 4))) = f2bf(s[nb][cb][r]);
                }
        bf16x8 pa[2];
        #pragma unroll
        for (int nb = 0; nb < 2; ++nb) {
            int off = (nb * 16 + lr) * 64 + lg * 16;
            pa[nb] = *(const bf16x8*)(pbase + (off ^ (((off >> 8) & 3) << 4)));
        }

        // ---- O += P V ----
        __builtin_amdgcn_s_setprio(1);
        #pragma unroll
        for (int db = 0; db < 16; ++db) {
            bf16x8 vf = *(const bf16x8*)(vB + (db * 16 + lr) * 80 + lg * 16);
            o[0][db] = mfma16(pa[0], vf, o[0][db]);
            o[1][db] = mfma16(pa[1], vf, o[1][db]);
        }
        __builtin_amdgcn_s_setprio(0);

        __builtin_amdgcn_s_barrier();                 // all waves done reading buf[cur]
        if (kt + 2 < NIT) stage(cur, kt + 2);         // overwrite buf[cur] with tile kt+2
    }

    // ---- intra-block merge: pair (w) <-> (w^4), same q-rows, two key-halves ----
    // 1) exchange m,l through P slots
    if (lr == 0) {
        #pragma unroll
        for (int nb = 0; nb < 2; ++nb)
            #pragma unroll
            for (int r = 0; r < 4; ++r) {
                int row = nb * 16 + lg * 4 + r;
                *(float*)(pbase + row * 4)       = mrow[nb][r];
                *(float*)(pbase + 128 + row * 4) = lrow[nb][r];
            }
    }
    asm volatile("s_waitcnt lgkmcnt(0)" ::: "memory");
    __builtin_amdgcn_s_barrier();

    const char* obase = smem + 147456 + (w ^ 4) * 2048;
    float sc[2][4], scO[2][4], lO[2][4];
    #pragma unroll
    for (int nb = 0; nb < 2; ++nb)
        #pragma unroll
        for (int r = 0; r < 4; ++r) {
            int row = nb * 16 + lg * 4 + r;
            float mo = *(const float*)(obase + row * 4);
            float ms = fmaxf(mrow[nb][r], mo);
            sc[nb][r]  = __builtin_amdgcn_exp2f(mrow[nb][r] - ms);
            scO[nb][r] = __builtin_amdgcn_exp2f(mo - ms);
            lO[nb][r]  = *(const float*)(obase + 128 + row * 4);
            mrow[nb][r] = ms;
        }

    // 2) exchange O in two 8-db halves through the (dead) stream-B buffers
    char* pairb = smem + 73728 + qw * 16384;          // 16KB per q-subtile pair
    #pragma unroll
    for (int h = 0; h < 2; ++h) {
        if (sidx == 1) {
            #pragma unroll
            for (int nb = 0; nb < 2; ++nb)
                #pragma unroll
                for (int dbl = 0; dbl < 8; ++dbl)
                    #pragma unroll
                    for (int r = 0; r < 4; ++r) {
                        int row = nb * 16 + lg * 4 + r;
                        *(float*)(pairb + (row * 128 + dbl * 16 + lr) * 4) =
                            o[nb][h * 8 + dbl][r] * sc[nb][r];
                    }
        }
        asm volatile("s_waitcnt lgkmcnt(0)" ::: "memory");
        __builtin_amdgcn_s_barrier();
        if (sidx == 0) {
            #pragma unroll
            for (int nb = 0; nb < 2; ++nb)
                #pragma unroll
                for (int dbl = 0; dbl < 8; ++dbl)
                    #pragma unroll
                    for (int r = 0; r < 4; ++r) {
                        int row = nb * 16 + lg * 4 + r;
                        o[nb][h * 8 + dbl][r] = o[nb][h * 8 + dbl][r] * sc[nb][r] +
                            *(const float*)(pairb + (row * 128 + dbl * 16 + lr) * 4);
                    }
        }
        asm volatile("s_waitcnt lgkmcnt(0)" ::: "memory");
        __builtin_amdgcn_s_barrier();
    }

    if (sidx == 0) {
        #pragma unroll
        for (int nb = 0; nb < 2; ++nb)
            #pragma unroll
            for (int r = 0; r < 4; ++r)
                lrow[nb][r] = lrow[nb][r] * sc[nb][r] + lO[nb][r] * scO[nb][r];

        unsigned short* Ob = Opart + (size_t)(b * 2 + hf) * CHD * NTOK;
        #pragma unroll
        for (int nb = 0; nb < 2; ++nb)
            #pragma unroll
            for (int db = 0; db < 16; ++db) {
                int d = db * 16 + lr;
                int n = n0 + qw * 32 + nb * 16 + lg * 4;
                u32x2 pk;
                pk[0] = (unsigned)f2bf(o[nb][db][0]) | ((unsigned)f2bf(o[nb][db][1]) << 16);
                pk[1] = (unsigned)f2bf(o[nb][db][2]) | ((unsigned)f2bf(o[nb][db][3]) << 16);
                *(u32x2*)(Ob + (size_t)d * NTOK + n) = pk;
            }
        if (lr == 0) {
            #pragma unroll
            for (int nb = 0; nb < 2; ++nb)
                #pragma unroll
                for (int r = 0; r < 4; ++r) {
                    int n = n0 + qw * 32 + nb * 16 + lg * 4 + r;
                    Mpart[(size_t)(b * 2 + hf) * NTOK + n] = mrow[nb][r];
                    Lpart[(size_t)(b * 2 + hf) * NTOK + n] = lrow[nb][r];
                }
        }
    }
}

// ---------------- kernel 4: merge the two KV-half partials ------------------
__global__ __launch_bounds__(256) void merge_kernel(
    const unsigned short* __restrict__ Opart,
    const float* __restrict__ Mpart, const float* __restrict__ Lpart,
    float* __restrict__ out)
{
    int tid = blockIdx.x * 256 + threadIdx.x;
    int n = (tid & 1023) * 4;
    int c = (tid >> 10) & 255;
    int b = tid >> 18;
    const size_t p0 = (size_t)(b * 2 + 0) * CHD * NTOK + (size_t)c * NTOK + n;
    const size_t p1 = (size_t)(b * 2 + 1) * CHD * NTOK + (size_t)c * NTOK + n;
    u32x2 o0 = *(const u32x2*)(Opart + p0);
    u32x2 o1 = *(const u32x2*)(Opart + p1);
    f32x4 m0 = *(const f32x4*)(Mpart + (size_t)(b * 2 + 0) * NTOK + n);
    f32x4 m1 = *(const f32x4*)(Mpart + (size_t)(b * 2 + 1) * NTOK + n);
    f32x4 l0 = *(const f32x4*)(Lpart + (size_t)(b * 2 + 0) * NTOK + n);
    f32x4 l1 = *(const f32x4*)(Lpart + (size_t)(b * 2 + 1) * NTOK + n);
    f32x4 res;
    #pragma unroll
    for (int r = 0; r < 4; ++r) {
        float mm = fmaxf(m0[r], m1[r]);
        float s0 = __builtin_amdgcn_exp2f(m0[r] - mm);
        float s1 = __builtin_amdgcn_exp2f(m1[r] - mm);
        float denom = l0[r] * s0 + l1[r] * s1;
        float f0 = bf2f((unsigned short)(o0[r >> 1] >> ((r & 1) * 16)));
        float f1 = bf2f((unsigned short)(o1[r >> 1] >> ((r & 1) * 16)));
        res[r] = (f0 * s0 + f1 * s1) / denom;
    }
    *(f32x4*)(out + (size_t)b * CHD * NTOK + (size_t)c * NTOK + n) = res;
}

// ---------------------------------------------------------------------------
extern "C" void kernel_launch(void* const* d_in, const int* in_sizes, int n_in,
                              void* d_out, int out_size, void* d_ws, size_t ws_size,
                              hipStream_t stream) {
    const float* xq = (const float*)d_in[0];
    const float* xk = (const float*)d_in[1];
    const float* xv = (const float*)d_in[2];
    const float* wq = (const float*)d_in[3];
    const float* bq = (const float*)d_in[4];
    const float* wk = (const float*)d_in[5];
    const float* bk = (const float*)d_in[6];
    const float* wv = (const float*)d_in[7];
    const float* bv = (const float*)d_in[8];

    char* ws = (char*)d_ws;
    unsigned short* wbf = (unsigned short*)ws;
    unsigned short* Qp  = (unsigned short*)(ws + 393216);
    unsigned short* Kp  = (unsigned short*)(ws + 393216 + 8388608);
    unsigned short* VTp = (unsigned short*)(ws + 393216 + 2 * 8388608);
    unsigned short* Op  = (unsigned short*)(ws + 393216 + 3 * 8388608);
    float* Mp = (float*)(ws + 393216 + 3 * 8388608 + 16777216);
    float* Lp = (float*)(ws + 393216 + 3 * 8388608 + 16777216 + 131072);

    hipLaunchKernelGGL(wconv_kernel, dim3(768), dim3(256), 0, stream, wq, wk, wv, wbf);
    hipLaunchKernelGGL(proj_kernel, dim3(256, 3), dim3(256), 0, stream,
                       xq, xk, xv, bq, bk, bv, wbf, Qp, Kp, VTp);
    hipLaunchKernelGGL(attn_kernel, dim3(256), dim3(512), 0, stream, Qp, Kp, VTp, Op, Mp, Lp);
    hipLaunchKernelGGL(merge_kernel, dim3(4096), dim3(256), 0, stream, Op, Mp, Lp, (float*)d_out);
}